// Round 1
// baseline (4110.418 us; speedup 1.0000x reference)
//
#include <hip/hip_runtime.h>
#include <hip/hip_bf16.h>

// Model dims
// B=8, S=256, C=4, L=256, E=256, H=8, DH=32, NL=2, NS=8

__device__ __forceinline__ float wave_sum(float v) {
    v += __shfl_xor(v, 32); v += __shfl_xor(v, 16); v += __shfl_xor(v, 8);
    v += __shfl_xor(v, 4);  v += __shfl_xor(v, 2);  v += __shfl_xor(v, 1);
    return v;
}
__device__ __forceinline__ float wave_max(float v) {
    v = fmaxf(v, __shfl_xor(v, 32)); v = fmaxf(v, __shfl_xor(v, 16));
    v = fmaxf(v, __shfl_xor(v, 8));  v = fmaxf(v, __shfl_xor(v, 4));
    v = fmaxf(v, __shfl_xor(v, 2));  v = fmaxf(v, __shfl_xor(v, 1));
    return v;
}

__global__ void init_kernel(unsigned* dmax) {
    if (threadIdx.x == 0) *dmax = 0u;
}

// Fused per-(b,s) CNN: conv1(4->128,k3,SAME)+relu -> conv2(128->256,k3,SAME)+relu
// -> max over L -> LayerNorm(no affine) -> feat[b,s,256]
// One block per (b,s). L processed in 4 chunks of 64 (h1 chunk in LDS, 45KB total).
__global__ __launch_bounds__(256) void cnn_kernel(
    const float* __restrict__ x, const float* __restrict__ w1, const float* __restrict__ b1,
    const float* __restrict__ w2, const float* __restrict__ b2, float* __restrict__ feat)
{
    __shared__ float xs[4][258];     // x padded: xs[ci][m] = x[ci][m-1], zeros at 0,257
    __shared__ float w1s[1536];      // conv1 weights for this segment
    __shared__ float h1c[128][66];   // conv1 output chunk: 64 interior + 2 halo cols
    __shared__ float cnnv[256];      // running max over L per out-channel
    __shared__ float red[4];

    const int tid  = threadIdx.x;
    const int bs   = blockIdx.x;           // b*256 + s
    const int s    = bs & 255;
    const int lane = tid & 63;
    const int grp  = __builtin_amdgcn_readfirstlane((int)(tid >> 6)); // wave id 0..3

    const float* xp = x + (size_t)bs * 1024;      // [4][256]
    for (int ci = 0; ci < 4; ci++) xs[ci][tid + 1] = xp[ci * 256 + tid];
    if (tid < 4) { xs[tid][0] = 0.f; xs[tid][257] = 0.f; }
    const float* w1p = w1 + (size_t)s * 1536;
    for (int i = tid; i < 1536; i += 256) w1s[i] = w1p[i];
    cnnv[tid] = -1e30f;

    const float* b1p = b1 + s * 128;
    const float* w2p = w2 + (size_t)s * (256 * 128 * 3);
    const float* b2p = b2 + s * 256;
    __syncthreads();

    for (int c = 0; c < 4; c++) {
        const int l0 = c * 64;
        __syncthreads();   // previous chunk's conv2 reads done before overwriting h1c

        // ---- conv1 interior: positions p=1..64  (l = l0 + lane) ----
        {
            float xr[4][3];
            const int l = l0 + lane;
#pragma unroll
            for (int ci = 0; ci < 4; ci++)
#pragma unroll
                for (int k = 0; k < 3; k++) xr[ci][k] = xs[ci][l + k];
            for (int it = 0; it < 32; it++) {
                const int co = grp + it * 4;   // wave-uniform
                float a = b1p[co];
                const float* w = &w1s[co * 12];
#pragma unroll
                for (int ci = 0; ci < 4; ci++)
#pragma unroll
                    for (int k = 0; k < 3; k++) a = fmaf(w[ci * 3 + k], xr[ci][k], a);
                h1c[co][lane + 1] = fmaxf(a, 0.f);
            }
        }
        // ---- conv1 halo columns p=0 (l=l0-1) and p=65 (l=l0+64) ----
        {
            const int which = tid >> 7;         // 0:left 1:right
            const int co = tid & 127;
            const int hl = which ? (l0 + 64) : (l0 - 1);
            float a = 0.f;
            if (hl >= 0 && hl <= 255) {
                a = b1p[co];
                const float* w = &w1s[co * 12];
#pragma unroll
                for (int ci = 0; ci < 4; ci++)
#pragma unroll
                    for (int k = 0; k < 3; k++) a = fmaf(w[ci * 3 + k], xs[ci][hl + k], a);
                a = fmaxf(a, 0.f);
            }
            h1c[co][which ? 65 : 0] = a;
        }
        __syncthreads();

        // ---- conv2 on chunk: wave `grp` handles out-channels [grp*64, grp*64+64) ----
        for (int cbl = 0; cbl < 8; cbl++) {
            const int cb = grp * 8 + cbl;               // wave-uniform co-block (8 channels)
            const float* wb = w2p + (size_t)cb * (8 * 384);
            float acc[8];
#pragma unroll
            for (int j = 0; j < 8; j++) acc[j] = 0.f;
#pragma unroll 4
            for (int ci = 0; ci < 128; ci++) {
                const float hm = h1c[ci][lane];
                const float h0 = h1c[ci][lane + 1];
                const float hp = h1c[ci][lane + 2];
                const float* wc = wb + ci * 3;
#pragma unroll
                for (int j = 0; j < 8; j++) {
                    acc[j] = fmaf(wc[j * 384 + 0], hm, acc[j]);
                    acc[j] = fmaf(wc[j * 384 + 1], h0, acc[j]);
                    acc[j] = fmaf(wc[j * 384 + 2], hp, acc[j]);
                }
            }
#pragma unroll
            for (int j = 0; j < 8; j++) {
                float v = wave_max(acc[j]);            // max over the 64 L-positions
                if (lane == 0) {
                    const int co = cb * 8 + j;
                    cnnv[co] = fmaxf(cnnv[co], v);
                }
            }
        }
    }
    __syncthreads();

    // ---- bias + relu + LayerNorm (no affine) over 256 channels ----
    const float val = fmaxf(cnnv[tid] + b2p[tid], 0.f);
    float t1 = wave_sum(val);
    if (lane == 0) red[tid >> 6] = t1;
    __syncthreads();
    const float mean = (red[0] + red[1] + red[2] + red[3]) * (1.f / 256.f);
    __syncthreads();
    const float dv = val - mean;
    float t2 = wave_sum(dv * dv);
    if (lane == 0) red[tid >> 6] = t2;
    __syncthreads();
    const float var = (red[0] + red[1] + red[2] + red[3]) * (1.f / 256.f);
    feat[(size_t)bs * 256 + tid] = dv * rsqrtf(var + 1e-5f);
}

// one wave per row of 256: sum of squares
__global__ __launch_bounds__(256) void sq_kernel(const float* __restrict__ feat, float* __restrict__ sq)
{
    const int tid = threadIdx.x, lane = tid & 63, wid = tid >> 6;
    const int row = blockIdx.x * 4 + wid;
    const float* xr = feat + (size_t)row * 256;
    float s = 0.f;
#pragma unroll
    for (int i = 0; i < 4; i++) { const float v = xr[lane + 64 * i]; s = fmaf(v, v, s); }
    s = wave_sum(s);
    if (lane == 0) sq[row] = s;
}

// pairwise distances for one (b, 32-i-tile, 16-j-tile); global max via atomic
__global__ __launch_bounds__(256) void dist_kernel(
    const float* __restrict__ feat, const float* __restrict__ sq,
    float* __restrict__ dist, unsigned* __restrict__ dmax)
{
    __shared__ float Fi[32][260];
    __shared__ float Fj[16][260];
    __shared__ float redm[4];
    const int tid = threadIdx.x;
    const int bid = blockIdx.x;
    const int b = bid >> 7, it = (bid >> 4) & 7, jt = bid & 15;
    const float* fb = feat + (size_t)b * 65536;
    for (int idx = tid; idx < 32 * 256; idx += 256) {
        const int r = idx >> 8, e = idx & 255;
        Fi[r][e] = fb[(it * 32 + r) * 256 + e];
    }
    for (int idx = tid; idx < 16 * 256; idx += 256) {
        const int r = idx >> 8, e = idx & 255;
        Fj[r][e] = fb[(jt * 16 + r) * 256 + e];
    }
    __syncthreads();
    const int ii = tid >> 3, j0 = (tid & 7) * 2;
    float acc[2] = {0.f, 0.f};
    for (int e = 0; e < 256; e += 4) {
        const float4 a = *(const float4*)&Fi[ii][e];
#pragma unroll
        for (int u = 0; u < 2; u++) {
            const float4 bv = *(const float4*)&Fj[j0 + u][e];
            acc[u] += a.x * bv.x + a.y * bv.y + a.z * bv.z + a.w * bv.w;
        }
    }
    const float sqi = sq[b * 256 + it * 32 + ii];
    float mymax = 0.f;
#pragma unroll
    for (int u = 0; u < 2; u++) {
        const float d2 = sqi + sq[b * 256 + jt * 16 + j0 + u] - 2.f * acc[u];
        const float d = sqrtf(fmaxf(d2, 0.f));
        dist[((size_t)b * 256 + it * 32 + ii) * 256 + jt * 16 + j0 + u] = d;
        mymax = fmaxf(mymax, d);
    }
    mymax = wave_max(mymax);
    if ((tid & 63) == 0) redm[tid >> 6] = mymax;
    __syncthreads();
    if (tid == 0) {
        const float m = fmaxf(fmaxf(redm[0], redm[1]), fmaxf(redm[2], redm[3]));
        atomicMax(dmax, __float_as_uint(m));
    }
}

// LayerNorm with affine, one wave per row of 256
__global__ __launch_bounds__(256) void ln_kernel(
    const float* __restrict__ x, const float* __restrict__ g, const float* __restrict__ bta,
    float* __restrict__ out)
{
    const int tid = threadIdx.x, lane = tid & 63, wid = tid >> 6;
    const int row = blockIdx.x * 4 + wid;
    const float* xr = x + (size_t)row * 256;
    float v[4];
#pragma unroll
    for (int i = 0; i < 4; i++) v[i] = xr[lane + 64 * i];
    float sm = wave_sum(v[0] + v[1] + v[2] + v[3]);
    const float mean = sm * (1.f / 256.f);
    float q = 0.f;
#pragma unroll
    for (int i = 0; i < 4; i++) { const float d = v[i] - mean; q = fmaf(d, d, q); }
    q = wave_sum(q);
    const float inv = rsqrtf(q * (1.f / 256.f) + 1e-5f);
    float* orow = out + (size_t)row * 256;
#pragma unroll
    for (int i = 0; i < 4; i++) {
        const int e = lane + 64 * i;
        orow[e] = (v[i] - mean) * inv * g[e] + bta[e];
    }
}

// C[M,N] = [relu]( A[M,K] @ W[K,N] + bias[N] [+ R[M,N]] )
// block: 8 rows x 256 cols; A via wave-uniform scalar loads, W coalesced.
__global__ __launch_bounds__(256) void gemm_kernel(
    const float* __restrict__ A, const float* __restrict__ W,
    const float* __restrict__ bias, const float* R, float* C,
    int M, int N, int K, int do_relu)
{
    const int m0 = blockIdx.x * 8;
    const int n  = blockIdx.y * 256 + threadIdx.x;
    const float* Ab = A + (size_t)m0 * K;
    float acc[8];
#pragma unroll
    for (int i = 0; i < 8; i++) acc[i] = 0.f;
    for (int k = 0; k < K; k += 4) {
        const float w0 = W[(size_t)(k + 0) * N + n];
        const float w1 = W[(size_t)(k + 1) * N + n];
        const float w2 = W[(size_t)(k + 2) * N + n];
        const float w3 = W[(size_t)(k + 3) * N + n];
#pragma unroll
        for (int mi = 0; mi < 8; mi++) {
            const float* ap = Ab + mi * K + k;   // uniform -> s_load_dwordx4
            acc[mi] = fmaf(ap[0], w0, acc[mi]);
            acc[mi] = fmaf(ap[1], w1, acc[mi]);
            acc[mi] = fmaf(ap[2], w2, acc[mi]);
            acc[mi] = fmaf(ap[3], w3, acc[mi]);
        }
    }
    const float bv = bias[n];
#pragma unroll
    for (int mi = 0; mi < 8; mi++) {
        float v = acc[mi] + bv;
        if (R) v += R[(size_t)(m0 + mi) * N + n];
        if (do_relu) v = fmaxf(v, 0.f);
        C[(size_t)(m0 + mi) * N + n] = v;
    }
}

// Fused attention for one (b, head, 64-query chunk). K in LDS, V from L2.
__global__ __launch_bounds__(256) void attn_kernel(
    const float* __restrict__ q, const float* __restrict__ k, const float* __restrict__ v,
    const float* __restrict__ dist, const unsigned* __restrict__ dmax,
    const float* __restrict__ bw, const float* __restrict__ bb,
    float* __restrict__ o)
{
    __shared__ float Ks[256][33];
    __shared__ float qs[32];
    __shared__ float as[256];
    __shared__ float part[8][32];
    __shared__ float red[4];

    const int tid = threadIdx.x, lane = tid & 63, wid = tid >> 6;
    const int bid = blockIdx.x;
    const int ic = bid & 3, hh = (bid >> 2) & 7, b = bid >> 5;

    const float dinv = 1.f / (__uint_as_float(*dmax) + 1e-6f);
    const float w0 = bw[0 * 8 + hh], w1 = bw[1 * 8 + hh], w2 = bw[2 * 8 + hh], w3 = bw[3 * 8 + hh];
    const float bbh = bb[hh];
    const float scale = 0.17677669529663687f;  // 1/sqrt(32)

    const float* kb = k + (size_t)b * 65536 + hh * 32;
    const float* vb = v + (size_t)b * 65536 + hh * 32;
    for (int idx = tid; idx < 8192; idx += 256) {
        const int j = idx >> 5, d = idx & 31;
        Ks[j][d] = kb[j * 256 + d];
    }
    __syncthreads();

    for (int ii = 0; ii < 64; ii++) {
        const int i = ic * 64 + ii;
        if (tid < 32) qs[tid] = q[((size_t)(b * 256 + i)) * 256 + hh * 32 + tid];
        __syncthreads();
        const int j = tid;
        float sc = 0.f;
#pragma unroll
        for (int d = 0; d < 32; d++) sc = fmaf(qs[d], Ks[j][d], sc);
        const float dn = dist[((size_t)(b * 256 + i)) * 256 + j] * dinv;
        const float rd = fabsf((float)(i - j)) * (1.f / 255.f);
        sc = sc * scale + w0 * dn + w1 * rd + w2 * (1.f - rd) + w3 * (1.f - dn) + bbh;
        // softmax over 256 j's
        float mx = wave_max(sc);
        if (lane == 0) red[wid] = mx;
        __syncthreads();
        mx = fmaxf(fmaxf(red[0], red[1]), fmaxf(red[2], red[3]));
        __syncthreads();
        const float ex = __expf(sc - mx);
        float smv = wave_sum(ex);
        if (lane == 0) red[wid] = smv;
        __syncthreads();
        const float denom = red[0] + red[1] + red[2] + red[3];
        as[j] = ex / denom;
        __syncthreads();
        // O = a @ V : thread (d = tid&31, jc = tid>>5) does 32 j's
        const int d = tid & 31, jc = tid >> 5;
        float p = 0.f;
#pragma unroll
        for (int jj = 0; jj < 32; jj++) {
            const int jv = jc * 32 + jj;
            p = fmaf(as[jv], vb[jv * 256 + d], p);
        }
        part[jc][d] = p;
        __syncthreads();
        if (tid < 32) {
            const float od = part[0][tid] + part[1][tid] + part[2][tid] + part[3][tid]
                           + part[4][tid] + part[5][tid] + part[6][tid] + part[7][tid];
            o[((size_t)(b * 256 + i)) * 256 + hh * 32 + tid] = od;
        }
        __syncthreads();
    }
}

// chunked max-pool over segments + final FC [2048 -> 2]
__global__ __launch_bounds__(256) void pool_fc_kernel(
    const float* __restrict__ h, const float* __restrict__ fcw,
    const float* __restrict__ fcb, float* __restrict__ out)
{
    __shared__ float red[8];
    const int b = blockIdx.x, tid = threadIdx.x, lane = tid & 63, wid = tid >> 6;
    float a0 = 0.f, a1 = 0.f;
    for (int ns = 0; ns < 8; ns++) {
        const float* hp = h + ((size_t)(b * 256 + ns * 32)) * 256 + tid;
        float m = hp[0];
#pragma unroll
        for (int r = 1; r < 32; r++) m = fmaxf(m, hp[(size_t)r * 256]);
        a0 = fmaf(m, fcw[(ns * 256 + tid) * 2 + 0], a0);
        a1 = fmaf(m, fcw[(ns * 256 + tid) * 2 + 1], a1);
    }
    a0 = wave_sum(a0);
    a1 = wave_sum(a1);
    if (lane == 0) { red[wid] = a0; red[4 + wid] = a1; }
    __syncthreads();
    if (tid == 0) out[b * 2 + 0] = red[0] + red[1] + red[2] + red[3] + fcb[0];
    if (tid == 1) out[b * 2 + 1] = red[4] + red[5] + red[6] + red[7] + fcb[1];
}

extern "C" void kernel_launch(void* const* d_in, const int* in_sizes, int n_in,
                              void* d_out, int out_size, void* d_ws, size_t ws_size,
                              hipStream_t stream)
{
    (void)in_sizes; (void)n_in; (void)out_size; (void)ws_size;
    const float* x       = (const float*)d_in[0];
    const float* conv1_w = (const float*)d_in[1];
    const float* conv1_b = (const float*)d_in[2];
    const float* conv2_w = (const float*)d_in[3];
    const float* conv2_b = (const float*)d_in[4];
    const float* ln1_g   = (const float*)d_in[5];
    const float* ln1_b   = (const float*)d_in[6];
    const float* wq = (const float*)d_in[7];  const float* bq = (const float*)d_in[8];
    const float* wk = (const float*)d_in[9];  const float* bk = (const float*)d_in[10];
    const float* wv = (const float*)d_in[11]; const float* bv = (const float*)d_in[12];
    const float* wo = (const float*)d_in[13]; const float* bo = (const float*)d_in[14];
    const float* bias_w = (const float*)d_in[15];
    const float* bias_b = (const float*)d_in[16];
    const float* ln2_g  = (const float*)d_in[17];
    const float* ln2_b  = (const float*)d_in[18];
    const float* ffn_w1 = (const float*)d_in[19]; const float* ffn_b1 = (const float*)d_in[20];
    const float* ffn_w2 = (const float*)d_in[21]; const float* ffn_b2 = (const float*)d_in[22];
    const float* fc_w   = (const float*)d_in[23]; const float* fc_b = (const float*)d_in[24];
    float* out = (float*)d_out;

    float* ws = (float*)d_ws;
    float* h    = ws;                 // [2048,256] feat -> residual stream
    float* hn   = h  + 524288;        // [2048,256]
    float* qb   = hn + 524288;        // [2048,256]
    float* kb   = qb + 524288;        // [2048,256]
    float* vb   = kb + 524288;        // [2048,256]
    float* ao   = vb + 524288;        // [2048,256]
    float* fm   = ao + 524288;        // [2048,512]
    float* dist = fm + 1048576;       // [8,256,256]
    float* sqv  = dist + 524288;      // [2048]
    unsigned* dmax = (unsigned*)(sqv + 2048);

    init_kernel<<<1, 64, 0, stream>>>(dmax);
    cnn_kernel<<<2048, 256, 0, stream>>>(x, conv1_w, conv1_b, conv2_w, conv2_b, h);
    sq_kernel<<<512, 256, 0, stream>>>(h, sqv);
    dist_kernel<<<1024, 256, 0, stream>>>(h, sqv, dist, dmax);

    for (int l = 0; l < 2; l++) {
        ln_kernel<<<512, 256, 0, stream>>>(h, ln1_g + l * 256, ln1_b + l * 256, hn);
        gemm_kernel<<<dim3(256, 1), 256, 0, stream>>>(hn, wq + (size_t)l * 65536, bq + l * 256, nullptr, qb, 2048, 256, 256, 0);
        gemm_kernel<<<dim3(256, 1), 256, 0, stream>>>(hn, wk + (size_t)l * 65536, bk + l * 256, nullptr, kb, 2048, 256, 256, 0);
        gemm_kernel<<<dim3(256, 1), 256, 0, stream>>>(hn, wv + (size_t)l * 65536, bv + l * 256, nullptr, vb, 2048, 256, 256, 0);
        attn_kernel<<<256, 256, 0, stream>>>(qb, kb, vb, dist, dmax, bias_w + l * 32, bias_b + l * 8, ao);
        gemm_kernel<<<dim3(256, 1), 256, 0, stream>>>(ao, wo + (size_t)l * 65536, bo + l * 256, h, h, 2048, 256, 256, 0);
        ln_kernel<<<512, 256, 0, stream>>>(h, ln2_g + l * 256, ln2_b + l * 256, hn);
        gemm_kernel<<<dim3(256, 2), 256, 0, stream>>>(hn, ffn_w1 + (size_t)l * 131072, ffn_b1 + l * 512, nullptr, fm, 2048, 512, 256, 1);
        gemm_kernel<<<dim3(256, 1), 256, 0, stream>>>(fm, ffn_w2 + (size_t)l * 131072, ffn_b2 + l * 256, h, h, 2048, 256, 512, 0);
    }
    pool_fc_kernel<<<8, 256, 0, stream>>>(h, fc_w, fc_b, out);
}

// Round 2
// 1262.357 us; speedup vs baseline: 3.2561x; 3.2561x over previous
//
#include <hip/hip_runtime.h>
#include <hip/hip_bf16.h>

// Model dims: B=8, S=256, C=4, L=256, E=256, H=8, DH=32, NL=2, NS=8

typedef float floatx4 __attribute__((ext_vector_type(4)));
typedef short bf16x8 __attribute__((ext_vector_type(8)));

__device__ __forceinline__ float wave_sum(float v) {
    v += __shfl_xor(v, 32); v += __shfl_xor(v, 16); v += __shfl_xor(v, 8);
    v += __shfl_xor(v, 4);  v += __shfl_xor(v, 2);  v += __shfl_xor(v, 1);
    return v;
}
__device__ __forceinline__ float wave_max(float v) {
    v = fmaxf(v, __shfl_xor(v, 32)); v = fmaxf(v, __shfl_xor(v, 16));
    v = fmaxf(v, __shfl_xor(v, 8));  v = fmaxf(v, __shfl_xor(v, 4));
    v = fmaxf(v, __shfl_xor(v, 2));  v = fmaxf(v, __shfl_xor(v, 1));
    return v;
}
__device__ __forceinline__ unsigned short f2bf(float v) {
    unsigned b = __float_as_uint(v);
    unsigned r = (b + 0x7fffu + ((b >> 16) & 1u)) >> 16;
    return (unsigned short)r;
}

__global__ void init_kernel(unsigned* dmax, unsigned* cnnmax) {
    const size_t i = (size_t)blockIdx.x * 256 + threadIdx.x;
    cnnmax[i] = 0u;
    if (i == 0) *dmax = 0u;
}

// w2 [S][256co][128ci][3tap] fp32 -> w2b [64 s_l][256co][384 kk=tap*128+ci] bf16
__global__ __launch_bounds__(256) void prep_w2_kernel(
    const float* __restrict__ w2, unsigned short* __restrict__ w2b, int s0)
{
    const int co = blockIdx.x;
    const int s_l = blockIdx.y;
    const int s = s0 + s_l;
    const float* src = w2 + ((size_t)(s * 256 + co)) * 384;
    unsigned short* dst = w2b + ((size_t)(s_l * 256 + co)) * 384;
    for (int kk = threadIdx.x; kk < 384; kk += 256) {
        const int ci = kk & 127, tap = kk >> 7;
        dst[kk] = f2bf(src[ci * 3 + tap]);
    }
}

// conv1 per (s_l, b): x[4][256] -> h1 bf16 stored as h1b[s_l][m=b*256+l][ci]
__global__ __launch_bounds__(256) void conv1_kernel(
    const float* __restrict__ x, const float* __restrict__ w1, const float* __restrict__ b1,
    unsigned short* __restrict__ h1b, int s0)
{
    __shared__ float xs[4][258];
    __shared__ float w1s[1536];
    __shared__ float h1c[128][65];
    const int tid = threadIdx.x;
    const int lane = tid & 63;
    const int grp = __builtin_amdgcn_readfirstlane((int)(tid >> 6));
    const int s_l = blockIdx.x;
    const int b = blockIdx.y;
    const int s = s0 + s_l;
    const int bs = b * 256 + s;

    const float* xp = x + (size_t)bs * 1024;
    for (int ci = 0; ci < 4; ci++) xs[ci][tid + 1] = xp[ci * 256 + tid];
    if (tid < 4) { xs[tid][0] = 0.f; xs[tid][257] = 0.f; }
    const float* w1p = w1 + (size_t)s * 1536;
    for (int i = tid; i < 1536; i += 256) w1s[i] = w1p[i];
    const float* b1p = b1 + s * 128;
    __syncthreads();

    const int ci2 = (tid & 63) * 2;
    const int q = tid >> 6;
    unsigned short* hb = h1b + ((size_t)(s_l * 2048 + b * 256)) * 128;

    for (int c = 0; c < 4; c++) {
        const int l0 = c * 64;
        if (c) __syncthreads();
        {
            float xr[4][3];
            const int l = l0 + lane;
#pragma unroll
            for (int ci = 0; ci < 4; ci++)
#pragma unroll
                for (int k = 0; k < 3; k++) xr[ci][k] = xs[ci][l + k];
            for (int it = 0; it < 32; it++) {
                const int co = grp + it * 4;
                float a = b1p[co];
                const float* w = &w1s[co * 12];
#pragma unroll
                for (int ci = 0; ci < 4; ci++)
#pragma unroll
                    for (int k = 0; k < 3; k++) a = fmaf(w[ci * 3 + k], xr[ci][k], a);
                h1c[co][lane] = fmaxf(a, 0.f);
            }
        }
        __syncthreads();
#pragma unroll
        for (int i = 0; i < 16; i++) {
            const int l_loc = q * 16 + i;
            const unsigned u0 = f2bf(h1c[ci2][l_loc]);
            const unsigned u1 = f2bf(h1c[ci2 + 1][l_loc]);
            *(unsigned*)(hb + (size_t)(l0 + l_loc) * 128 + ci2) = u0 | (u1 << 16);
        }
    }
}

// conv2 implicit GEMM, bf16 MFMA. Block: 512 thr (8 waves), tile 256co x 128m.
// Wave wv: wm=wv&3 -> co strip [wm*64,+64); wn=wv>>2 -> m half [wn*64,+64).
// h1 tile (with k=3 halo rows, zeros at segment edges) staged in LDS once.
__global__ __launch_bounds__(512) void conv2_mfma_kernel(
    const unsigned short* __restrict__ w2b,   // [64][256][384]
    const unsigned short* __restrict__ h1b,   // [64][2048][128]
    const float* __restrict__ b2,             // [256][256]
    unsigned* __restrict__ cnnmax,            // [2048][256] f32-as-u32, relu'd
    int s0)
{
    __shared__ unsigned short Hs[130 * 136];
    const int tid = threadIdx.x;
    const int lane = tid & 63;
    const int wv = __builtin_amdgcn_readfirstlane((int)(tid >> 6));
    const int wm = wv & 3, wn = wv >> 2;
    const int nt = blockIdx.x;               // 0..15
    const int s_l = blockIdx.y;              // 0..63
    const int s = s0 + s_l;
    const int m0 = nt * 128;
    const int bglob = m0 >> 8;
    const int l0 = m0 & 255;
    const int lr = lane & 15;
    const int quad = lane >> 4;
    const int qk = quad * 8;

    // stage 130 rows (l0-1 .. l0+128) x 128 ci
    const unsigned short* hbase = h1b + ((size_t)(s_l * 2048 + bglob * 256)) * 128;
    for (int idx = tid; idx < 2080; idx += 512) {
        const int rl = idx >> 4;
        const int ci8 = (idx & 15) * 8;
        const int srcl = l0 + rl - 1;
        bf16x8 v = {};
        if (srcl >= 0 && srcl < 256)
            v = *(const bf16x8*)(hbase + (size_t)srcl * 128 + ci8);
        *(bf16x8*)(&Hs[rl * 136 + ci8]) = v;
    }
    __syncthreads();

    floatx4 acc[4][4];
#pragma unroll
    for (int r = 0; r < 4; r++)
#pragma unroll
        for (int c = 0; c < 4; c++) acc[r][c] = (floatx4){0.f, 0.f, 0.f, 0.f};

    const int co_base = wm * 64;
    const unsigned short* wp = w2b + ((size_t)(s_l * 256 + co_base + lr)) * 384 + qk;
    const int nb = wn * 64;

#pragma unroll
    for (int tap = 0; tap < 3; tap++) {
#pragma unroll
        for (int ci0 = 0; ci0 < 128; ci0 += 32) {
            const int kk0 = tap * 128 + ci0;
            bf16x8 a[4], bb[4];
#pragma unroll
            for (int r = 0; r < 4; r++)
                a[r] = *(const bf16x8*)(wp + r * (16 * 384) + kk0);
#pragma unroll
            for (int c = 0; c < 4; c++) {
                const int rl = nb + c * 16 + lr + tap;
                bb[c] = *(const bf16x8*)(&Hs[rl * 136 + ci0 + qk]);
            }
#pragma unroll
            for (int r = 0; r < 4; r++)
#pragma unroll
                for (int c = 0; c < 4; c++)
                    acc[r][c] = __builtin_amdgcn_mfma_f32_16x16x32_bf16(a[r], bb[c], acc[r][c], 0, 0, 0);
        }
    }

    // epilogue: relu(acc+bias) -> max over this wave's 64 m -> atomicMax into cnnmax
    const float* b2s = b2 + s * 256;
    unsigned* cmrow = cnnmax + ((size_t)(bglob * 256 + s)) * 256;
#pragma unroll
    for (int r = 0; r < 4; r++) {
#pragma unroll
        for (int e = 0; e < 4; e++) {
            const int co = co_base + r * 16 + quad * 4 + e;
            const float bias = b2s[co];
            float mv = 0.f;   // relu floor
#pragma unroll
            for (int c = 0; c < 4; c++) mv = fmaxf(mv, acc[r][c][e] + bias);
            mv = fmaxf(mv, __shfl_xor(mv, 1));
            mv = fmaxf(mv, __shfl_xor(mv, 2));
            mv = fmaxf(mv, __shfl_xor(mv, 4));
            mv = fmaxf(mv, __shfl_xor(mv, 8));
            if (lr == 0) atomicMax(&cmrow[co], __float_as_uint(mv));
        }
    }
}

// LayerNorm (no affine) from cnnmax -> feat
__global__ __launch_bounds__(256) void ln0_kernel(const unsigned* __restrict__ cm, float* __restrict__ out)
{
    const int tid = threadIdx.x, lane = tid & 63, wid = tid >> 6;
    const int row = blockIdx.x * 4 + wid;
    const unsigned* xr = cm + (size_t)row * 256;
    float v[4];
#pragma unroll
    for (int i = 0; i < 4; i++) v[i] = __uint_as_float(xr[lane + 64 * i]);
    float sm = wave_sum(v[0] + v[1] + v[2] + v[3]);
    const float mean = sm * (1.f / 256.f);
    float qv = 0.f;
#pragma unroll
    for (int i = 0; i < 4; i++) { const float d = v[i] - mean; qv = fmaf(d, d, qv); }
    qv = wave_sum(qv);
    const float inv = rsqrtf(qv * (1.f / 256.f) + 1e-5f);
    float* orow = out + (size_t)row * 256;
#pragma unroll
    for (int i = 0; i < 4; i++) orow[lane + 64 * i] = (v[i] - mean) * inv;
}

// one wave per row of 256: sum of squares
__global__ __launch_bounds__(256) void sq_kernel(const float* __restrict__ feat, float* __restrict__ sq)
{
    const int tid = threadIdx.x, lane = tid & 63, wid = tid >> 6;
    const int row = blockIdx.x * 4 + wid;
    const float* xr = feat + (size_t)row * 256;
    float s = 0.f;
#pragma unroll
    for (int i = 0; i < 4; i++) { const float v = xr[lane + 64 * i]; s = fmaf(v, v, s); }
    s = wave_sum(s);
    if (lane == 0) sq[row] = s;
}

// pairwise distances for one (b, 32-i-tile, 16-j-tile); global max via atomic
__global__ __launch_bounds__(256) void dist_kernel(
    const float* __restrict__ feat, const float* __restrict__ sq,
    float* __restrict__ dist, unsigned* __restrict__ dmax)
{
    __shared__ float Fi[32][260];
    __shared__ float Fj[16][260];
    __shared__ float redm[4];
    const int tid = threadIdx.x;
    const int bid = blockIdx.x;
    const int b = bid >> 7, it = (bid >> 4) & 7, jt = bid & 15;
    const float* fb = feat + (size_t)b * 65536;
    for (int idx = tid; idx < 32 * 256; idx += 256) {
        const int r = idx >> 8, e = idx & 255;
        Fi[r][e] = fb[(it * 32 + r) * 256 + e];
    }
    for (int idx = tid; idx < 16 * 256; idx += 256) {
        const int r = idx >> 8, e = idx & 255;
        Fj[r][e] = fb[(jt * 16 + r) * 256 + e];
    }
    __syncthreads();
    const int ii = tid >> 3, j0 = (tid & 7) * 2;
    float acc[2] = {0.f, 0.f};
    for (int e = 0; e < 256; e += 4) {
        const float4 a = *(const float4*)&Fi[ii][e];
#pragma unroll
        for (int u = 0; u < 2; u++) {
            const float4 bv = *(const float4*)&Fj[j0 + u][e];
            acc[u] += a.x * bv.x + a.y * bv.y + a.z * bv.z + a.w * bv.w;
        }
    }
    const float sqi = sq[b * 256 + it * 32 + ii];
    float mymax = 0.f;
#pragma unroll
    for (int u = 0; u < 2; u++) {
        const float d2 = sqi + sq[b * 256 + jt * 16 + j0 + u] - 2.f * acc[u];
        const float d = sqrtf(fmaxf(d2, 0.f));
        dist[((size_t)b * 256 + it * 32 + ii) * 256 + jt * 16 + j0 + u] = d;
        mymax = fmaxf(mymax, d);
    }
    mymax = wave_max(mymax);
    if ((tid & 63) == 0) redm[tid >> 6] = mymax;
    __syncthreads();
    if (tid == 0) {
        const float m = fmaxf(fmaxf(redm[0], redm[1]), fmaxf(redm[2], redm[3]));
        atomicMax(dmax, __float_as_uint(m));
    }
}

// LayerNorm with affine, one wave per row of 256
__global__ __launch_bounds__(256) void ln_kernel(
    const float* __restrict__ x, const float* __restrict__ g, const float* __restrict__ bta,
    float* __restrict__ out)
{
    const int tid = threadIdx.x, lane = tid & 63, wid = tid >> 6;
    const int row = blockIdx.x * 4 + wid;
    const float* xr = x + (size_t)row * 256;
    float v[4];
#pragma unroll
    for (int i = 0; i < 4; i++) v[i] = xr[lane + 64 * i];
    float sm = wave_sum(v[0] + v[1] + v[2] + v[3]);
    const float mean = sm * (1.f / 256.f);
    float q = 0.f;
#pragma unroll
    for (int i = 0; i < 4; i++) { const float d = v[i] - mean; q = fmaf(d, d, q); }
    q = wave_sum(q);
    const float inv = rsqrtf(q * (1.f / 256.f) + 1e-5f);
    float* orow = out + (size_t)row * 256;
#pragma unroll
    for (int i = 0; i < 4; i++) {
        const int e = lane + 64 * i;
        orow[e] = (v[i] - mean) * inv * g[e] + bta[e];
    }
}

// C[M,N] = [relu]( A[M,K] @ W[K,N] + bias[N] [+ R[M,N]] )
__global__ __launch_bounds__(256) void gemm_kernel(
    const float* __restrict__ A, const float* __restrict__ W,
    const float* __restrict__ bias, const float* R, float* C,
    int M, int N, int K, int do_relu)
{
    const int m0 = blockIdx.x * 8;
    const int n  = blockIdx.y * 256 + threadIdx.x;
    const float* Ab = A + (size_t)m0 * K;
    float acc[8];
#pragma unroll
    for (int i = 0; i < 8; i++) acc[i] = 0.f;
    for (int k = 0; k < K; k += 4) {
        const float w0 = W[(size_t)(k + 0) * N + n];
        const float w1 = W[(size_t)(k + 1) * N + n];
        const float w2 = W[(size_t)(k + 2) * N + n];
        const float w3 = W[(size_t)(k + 3) * N + n];
#pragma unroll
        for (int mi = 0; mi < 8; mi++) {
            const float* ap = Ab + mi * K + k;
            acc[mi] = fmaf(ap[0], w0, acc[mi]);
            acc[mi] = fmaf(ap[1], w1, acc[mi]);
            acc[mi] = fmaf(ap[2], w2, acc[mi]);
            acc[mi] = fmaf(ap[3], w3, acc[mi]);
        }
    }
    const float bv = bias[n];
#pragma unroll
    for (int mi = 0; mi < 8; mi++) {
        float v = acc[mi] + bv;
        if (R) v += R[(size_t)(m0 + mi) * N + n];
        if (do_relu) v = fmaxf(v, 0.f);
        C[(size_t)(m0 + mi) * N + n] = v;
    }
}

// Fused attention for one (b, head, 64-query chunk). K in LDS, V from L2.
__global__ __launch_bounds__(256) void attn_kernel(
    const float* __restrict__ q, const float* __restrict__ k, const float* __restrict__ v,
    const float* __restrict__ dist, const unsigned* __restrict__ dmax,
    const float* __restrict__ bw, const float* __restrict__ bb,
    float* __restrict__ o)
{
    __shared__ float Ks[256][33];
    __shared__ float qs[32];
    __shared__ float as[256];
    __shared__ float part[8][32];
    __shared__ float red[4];

    const int tid = threadIdx.x, lane = tid & 63, wid = tid >> 6;
    const int bid = blockIdx.x;
    const int ic = bid & 3, hh = (bid >> 2) & 7, b = bid >> 5;

    const float dinv = 1.f / (__uint_as_float(*dmax) + 1e-6f);
    const float w0 = bw[0 * 8 + hh], w1 = bw[1 * 8 + hh], w2 = bw[2 * 8 + hh], w3 = bw[3 * 8 + hh];
    const float bbh = bb[hh];
    const float scale = 0.17677669529663687f;

    const float* kb = k + (size_t)b * 65536 + hh * 32;
    const float* vb = v + (size_t)b * 65536 + hh * 32;
    for (int idx = tid; idx < 8192; idx += 256) {
        const int j = idx >> 5, d = idx & 31;
        Ks[j][d] = kb[j * 256 + d];
    }
    __syncthreads();

    for (int ii = 0; ii < 64; ii++) {
        const int i = ic * 64 + ii;
        if (tid < 32) qs[tid] = q[((size_t)(b * 256 + i)) * 256 + hh * 32 + tid];
        __syncthreads();
        const int j = tid;
        float sc = 0.f;
#pragma unroll
        for (int d = 0; d < 32; d++) sc = fmaf(qs[d], Ks[j][d], sc);
        const float dn = dist[((size_t)(b * 256 + i)) * 256 + j] * dinv;
        const float rd = fabsf((float)(i - j)) * (1.f / 255.f);
        sc = sc * scale + w0 * dn + w1 * rd + w2 * (1.f - rd) + w3 * (1.f - dn) + bbh;
        float mx = wave_max(sc);
        if (lane == 0) red[wid] = mx;
        __syncthreads();
        mx = fmaxf(fmaxf(red[0], red[1]), fmaxf(red[2], red[3]));
        __syncthreads();
        const float ex = __expf(sc - mx);
        float smv = wave_sum(ex);
        if (lane == 0) red[wid] = smv;
        __syncthreads();
        const float denom = red[0] + red[1] + red[2] + red[3];
        as[j] = ex / denom;
        __syncthreads();
        const int d = tid & 31, jc = tid >> 5;
        float p = 0.f;
#pragma unroll
        for (int jj = 0; jj < 32; jj++) {
            const int jv = jc * 32 + jj;
            p = fmaf(as[jv], vb[jv * 256 + d], p);
        }
        part[jc][d] = p;
        __syncthreads();
        if (tid < 32) {
            const float od = part[0][tid] + part[1][tid] + part[2][tid] + part[3][tid]
                           + part[4][tid] + part[5][tid] + part[6][tid] + part[7][tid];
            o[((size_t)(b * 256 + i)) * 256 + hh * 32 + tid] = od;
        }
        __syncthreads();
    }
}

// chunked max-pool over segments + final FC [2048 -> 2]
__global__ __launch_bounds__(256) void pool_fc_kernel(
    const float* __restrict__ h, const float* __restrict__ fcw,
    const float* __restrict__ fcb, float* __restrict__ out)
{
    __shared__ float red[8];
    const int b = blockIdx.x, tid = threadIdx.x, lane = tid & 63, wid = tid >> 6;
    float a0 = 0.f, a1 = 0.f;
    for (int ns = 0; ns < 8; ns++) {
        const float* hp = h + ((size_t)(b * 256 + ns * 32)) * 256 + tid;
        float m = hp[0];
#pragma unroll
        for (int r = 1; r < 32; r++) m = fmaxf(m, hp[(size_t)r * 256]);
        a0 = fmaf(m, fcw[(ns * 256 + tid) * 2 + 0], a0);
        a1 = fmaf(m, fcw[(ns * 256 + tid) * 2 + 1], a1);
    }
    a0 = wave_sum(a0);
    a1 = wave_sum(a1);
    if (lane == 0) { red[wid] = a0; red[4 + wid] = a1; }
    __syncthreads();
    if (tid == 0) out[b * 2 + 0] = red[0] + red[1] + red[2] + red[3] + fcb[0];
    if (tid == 1) out[b * 2 + 1] = red[4] + red[5] + red[6] + red[7] + fcb[1];
}

extern "C" void kernel_launch(void* const* d_in, const int* in_sizes, int n_in,
                              void* d_out, int out_size, void* d_ws, size_t ws_size,
                              hipStream_t stream)
{
    (void)in_sizes; (void)n_in; (void)out_size; (void)ws_size;
    const float* x       = (const float*)d_in[0];
    const float* conv1_w = (const float*)d_in[1];
    const float* conv1_b = (const float*)d_in[2];
    const float* conv2_w = (const float*)d_in[3];
    const float* conv2_b = (const float*)d_in[4];
    const float* ln1_g   = (const float*)d_in[5];
    const float* ln1_b   = (const float*)d_in[6];
    const float* wq = (const float*)d_in[7];  const float* bq = (const float*)d_in[8];
    const float* wk = (const float*)d_in[9];  const float* bk = (const float*)d_in[10];
    const float* wv = (const float*)d_in[11]; const float* bv = (const float*)d_in[12];
    const float* wo = (const float*)d_in[13]; const float* bo = (const float*)d_in[14];
    const float* bias_w = (const float*)d_in[15];
    const float* bias_b = (const float*)d_in[16];
    const float* ln2_g  = (const float*)d_in[17];
    const float* ln2_b  = (const float*)d_in[18];
    const float* ffn_w1 = (const float*)d_in[19]; const float* ffn_b1 = (const float*)d_in[20];
    const float* ffn_w2 = (const float*)d_in[21]; const float* ffn_b2 = (const float*)d_in[22];
    const float* fc_w   = (const float*)d_in[23]; const float* fc_b = (const float*)d_in[24];
    float* out = (float*)d_out;

    float* ws = (float*)d_ws;
    float* h    = ws;                 // [2048,256]
    float* hn   = h  + 524288;
    float* qb   = hn + 524288;
    float* kb   = qb + 524288;
    float* vb   = kb + 524288;
    float* ao   = vb + 524288;
    float* fm   = ao + 524288;        // [2048,512]
    float* dist = fm + 1048576;       // [8,256,256]
    float* sqv  = dist + 524288;      // [2048]
    unsigned* dmax = (unsigned*)(sqv + 2048);
    unsigned* cnnmax = (unsigned*)(sqv + 2048 + 16);          // [2048,256]
    unsigned short* w2b = (unsigned short*)(sqv + 2048 + 16 + 524288);  // 64*256*384 bf16
    unsigned short* h1b = w2b + 64 * 256 * 384;                         // 64*2048*128 bf16

    init_kernel<<<2048, 256, 0, stream>>>(dmax, cnnmax);
    for (int g = 0; g < 4; g++) {
        const int s0 = g * 64;
        prep_w2_kernel<<<dim3(256, 64), 256, 0, stream>>>(conv2_w, w2b, s0);
        conv1_kernel<<<dim3(64, 8), 256, 0, stream>>>(x, conv1_w, conv1_b, h1b, s0);
        conv2_mfma_kernel<<<dim3(16, 64), 512, 0, stream>>>(w2b, h1b, conv2_b, cnnmax, s0);
    }
    ln0_kernel<<<512, 256, 0, stream>>>(cnnmax, h);
    sq_kernel<<<512, 256, 0, stream>>>(h, sqv);
    dist_kernel<<<1024, 256, 0, stream>>>(h, sqv, dist, dmax);

    for (int l = 0; l < 2; l++) {
        ln_kernel<<<512, 256, 0, stream>>>(h, ln1_g + l * 256, ln1_b + l * 256, hn);
        gemm_kernel<<<dim3(256, 1), 256, 0, stream>>>(hn, wq + (size_t)l * 65536, bq + l * 256, nullptr, qb, 2048, 256, 256, 0);
        gemm_kernel<<<dim3(256, 1), 256, 0, stream>>>(hn, wk + (size_t)l * 65536, bk + l * 256, nullptr, kb, 2048, 256, 256, 0);
        gemm_kernel<<<dim3(256, 1), 256, 0, stream>>>(hn, wv + (size_t)l * 65536, bv + l * 256, nullptr, vb, 2048, 256, 256, 0);
        attn_kernel<<<256, 256, 0, stream>>>(qb, kb, vb, dist, dmax, bias_w + l * 32, bias_b + l * 8, ao);
        gemm_kernel<<<dim3(256, 1), 256, 0, stream>>>(ao, wo + (size_t)l * 65536, bo + l * 256, h, h, 2048, 256, 256, 0);
        ln_kernel<<<512, 256, 0, stream>>>(h, ln2_g + l * 256, ln2_b + l * 256, hn);
        gemm_kernel<<<dim3(256, 2), 256, 0, stream>>>(hn, ffn_w1 + (size_t)l * 131072, ffn_b1 + l * 512, nullptr, fm, 2048, 512, 256, 1);
        gemm_kernel<<<dim3(256, 1), 256, 0, stream>>>(fm, ffn_w2 + (size_t)l * 131072, ffn_b2 + l * 256, h, h, 2048, 256, 512, 0);
    }
    pool_fc_kernel<<<8, 256, 0, stream>>>(h, fc_w, fc_b, out);
}

// Round 3
// 722.456 us; speedup vs baseline: 5.6895x; 1.7473x over previous
//
#include <hip/hip_runtime.h>
#include <hip/hip_bf16.h>

// Model dims: B=8, S=256, C=4, L=256, E=256, H=8, DH=32, NL=2, NS=8

typedef float floatx4 __attribute__((ext_vector_type(4)));
typedef short bf16x8 __attribute__((ext_vector_type(8)));

__device__ __forceinline__ float wave_sum(float v) {
    v += __shfl_xor(v, 32); v += __shfl_xor(v, 16); v += __shfl_xor(v, 8);
    v += __shfl_xor(v, 4);  v += __shfl_xor(v, 2);  v += __shfl_xor(v, 1);
    return v;
}
__device__ __forceinline__ float wave_max(float v) {
    v = fmaxf(v, __shfl_xor(v, 32)); v = fmaxf(v, __shfl_xor(v, 16));
    v = fmaxf(v, __shfl_xor(v, 8));  v = fmaxf(v, __shfl_xor(v, 4));
    v = fmaxf(v, __shfl_xor(v, 2));  v = fmaxf(v, __shfl_xor(v, 1));
    return v;
}
__device__ __forceinline__ unsigned short f2bf(float v) {
    unsigned b = __float_as_uint(v);
    unsigned r = (b + 0x7fffu + ((b >> 16) & 1u)) >> 16;
    return (unsigned short)r;
}

__global__ void init_kernel(unsigned* dmax, unsigned* cnnmax) {
    const size_t i = (size_t)blockIdx.x * 256 + threadIdx.x;
    cnnmax[i] = 0u;
    if (i == 0) *dmax = 0u;
}

// w2 [S][256co][128ci][3tap] fp32 -> w2b [64 s_l][256co][384 kk=tap*128+ci] bf16
__global__ __launch_bounds__(256) void prep_w2_kernel(
    const float* __restrict__ w2, unsigned short* __restrict__ w2b, int s0)
{
    const int co = blockIdx.x;
    const int s_l = blockIdx.y;
    const int s = s0 + s_l;
    const float* src = w2 + ((size_t)(s * 256 + co)) * 384;
    unsigned short* dst = w2b + ((size_t)(s_l * 256 + co)) * 384;
    for (int kk = threadIdx.x; kk < 384; kk += 256) {
        const int ci = kk & 127, tap = kk >> 7;
        dst[kk] = f2bf(src[ci * 3 + tap]);
    }
}

// conv1 per (s_l, b): x[4][256] -> h1 bf16 stored as h1b[s_l][m=b*256+l][ci]
__global__ __launch_bounds__(256) void conv1_kernel(
    const float* __restrict__ x, const float* __restrict__ w1, const float* __restrict__ b1,
    unsigned short* __restrict__ h1b, int s0)
{
    __shared__ float xs[4][258];
    __shared__ float w1s[1536];
    __shared__ float h1c[128][65];
    const int tid = threadIdx.x;
    const int lane = tid & 63;
    const int grp = __builtin_amdgcn_readfirstlane((int)(tid >> 6));
    const int s_l = blockIdx.x;
    const int b = blockIdx.y;
    const int s = s0 + s_l;
    const int bs = b * 256 + s;

    const float* xp = x + (size_t)bs * 1024;
    for (int ci = 0; ci < 4; ci++) xs[ci][tid + 1] = xp[ci * 256 + tid];
    if (tid < 4) { xs[tid][0] = 0.f; xs[tid][257] = 0.f; }
    const float* w1p = w1 + (size_t)s * 1536;
    for (int i = tid; i < 1536; i += 256) w1s[i] = w1p[i];
    const float* b1p = b1 + s * 128;
    __syncthreads();

    const int ci2 = (tid & 63) * 2;
    const int q = tid >> 6;
    unsigned short* hb = h1b + ((size_t)(s_l * 2048 + b * 256)) * 128;

    for (int c = 0; c < 4; c++) {
        const int l0 = c * 64;
        if (c) __syncthreads();
        {
            float xr[4][3];
            const int l = l0 + lane;
#pragma unroll
            for (int ci = 0; ci < 4; ci++)
#pragma unroll
                for (int k = 0; k < 3; k++) xr[ci][k] = xs[ci][l + k];
            for (int it = 0; it < 32; it++) {
                const int co = grp + it * 4;
                float a = b1p[co];
                const float* w = &w1s[co * 12];
#pragma unroll
                for (int ci = 0; ci < 4; ci++)
#pragma unroll
                    for (int k = 0; k < 3; k++) a = fmaf(w[ci * 3 + k], xr[ci][k], a);
                h1c[co][lane] = fmaxf(a, 0.f);
            }
        }
        __syncthreads();
#pragma unroll
        for (int i = 0; i < 16; i++) {
            const int l_loc = q * 16 + i;
            const unsigned u0 = f2bf(h1c[ci2][l_loc]);
            const unsigned u1 = f2bf(h1c[ci2 + 1][l_loc]);
            *(unsigned*)(hb + (size_t)(l0 + l_loc) * 128 + ci2) = u0 | (u1 << 16);
        }
    }
}

// conv2 implicit GEMM, bf16 MFMA. Block: 512 thr (8 waves), tile 256co x 128m.
__global__ __launch_bounds__(512) void conv2_mfma_kernel(
    const unsigned short* __restrict__ w2b,   // [64][256][384]
    const unsigned short* __restrict__ h1b,   // [64][2048][128]
    const float* __restrict__ b2,             // [256][256]
    unsigned* __restrict__ cnnmax,            // [2048][256] f32-as-u32, relu'd
    int s0)
{
    __shared__ unsigned short Hs[130 * 136];
    const int tid = threadIdx.x;
    const int lane = tid & 63;
    const int wv = __builtin_amdgcn_readfirstlane((int)(tid >> 6));
    const int wm = wv & 3, wn = wv >> 2;
    const int nt = blockIdx.x;               // 0..15
    const int s_l = blockIdx.y;              // 0..63
    const int s = s0 + s_l;
    const int m0 = nt * 128;
    const int bglob = m0 >> 8;
    const int l0 = m0 & 255;
    const int lr = lane & 15;
    const int quad = lane >> 4;
    const int qk = quad * 8;

    const unsigned short* hbase = h1b + ((size_t)(s_l * 2048 + bglob * 256)) * 128;
    for (int idx = tid; idx < 2080; idx += 512) {
        const int rl = idx >> 4;
        const int ci8 = (idx & 15) * 8;
        const int srcl = l0 + rl - 1;
        bf16x8 v = {};
        if (srcl >= 0 && srcl < 256)
            v = *(const bf16x8*)(hbase + (size_t)srcl * 128 + ci8);
        *(bf16x8*)(&Hs[rl * 136 + ci8]) = v;
    }
    __syncthreads();

    floatx4 acc[4][4];
#pragma unroll
    for (int r = 0; r < 4; r++)
#pragma unroll
        for (int c = 0; c < 4; c++) acc[r][c] = (floatx4){0.f, 0.f, 0.f, 0.f};

    const int co_base = wm * 64;
    const unsigned short* wp = w2b + ((size_t)(s_l * 256 + co_base + lr)) * 384 + qk;
    const int nb = wn * 64;

#pragma unroll
    for (int tap = 0; tap < 3; tap++) {
#pragma unroll
        for (int ci0 = 0; ci0 < 128; ci0 += 32) {
            const int kk0 = tap * 128 + ci0;
            bf16x8 a[4], bb[4];
#pragma unroll
            for (int r = 0; r < 4; r++)
                a[r] = *(const bf16x8*)(wp + r * (16 * 384) + kk0);
#pragma unroll
            for (int c = 0; c < 4; c++) {
                const int rl = nb + c * 16 + lr + tap;
                bb[c] = *(const bf16x8*)(&Hs[rl * 136 + ci0 + qk]);
            }
#pragma unroll
            for (int r = 0; r < 4; r++)
#pragma unroll
                for (int c = 0; c < 4; c++)
                    acc[r][c] = __builtin_amdgcn_mfma_f32_16x16x32_bf16(a[r], bb[c], acc[r][c], 0, 0, 0);
        }
    }

    const float* b2s = b2 + s * 256;
    unsigned* cmrow = cnnmax + ((size_t)(bglob * 256 + s)) * 256;
#pragma unroll
    for (int r = 0; r < 4; r++) {
#pragma unroll
        for (int e = 0; e < 4; e++) {
            const int co = co_base + r * 16 + quad * 4 + e;
            const float bias = b2s[co];
            float mv = 0.f;
#pragma unroll
            for (int c = 0; c < 4; c++) mv = fmaxf(mv, acc[r][c][e] + bias);
            mv = fmaxf(mv, __shfl_xor(mv, 1));
            mv = fmaxf(mv, __shfl_xor(mv, 2));
            mv = fmaxf(mv, __shfl_xor(mv, 4));
            mv = fmaxf(mv, __shfl_xor(mv, 8));
            if (lr == 0) atomicMax(&cmrow[co], __float_as_uint(mv));
        }
    }
}

// LayerNorm (no affine) from cnnmax -> feat(h); fused sum-of-squares -> sqv
__global__ __launch_bounds__(256) void ln0_kernel(
    const unsigned* __restrict__ cm, float* __restrict__ out, float* __restrict__ sqv)
{
    const int tid = threadIdx.x, lane = tid & 63, wid = tid >> 6;
    const int row = blockIdx.x * 4 + wid;
    const unsigned* xr = cm + (size_t)row * 256;
    float v[4];
#pragma unroll
    for (int i = 0; i < 4; i++) v[i] = __uint_as_float(xr[lane + 64 * i]);
    float sm = wave_sum(v[0] + v[1] + v[2] + v[3]);
    const float mean = sm * (1.f / 256.f);
    float qv = 0.f;
#pragma unroll
    for (int i = 0; i < 4; i++) { const float d = v[i] - mean; qv = fmaf(d, d, qv); }
    qv = wave_sum(qv);
    const float inv = rsqrtf(qv * (1.f / 256.f) + 1e-5f);
    float* orow = out + (size_t)row * 256;
#pragma unroll
    for (int i = 0; i < 4; i++) orow[lane + 64 * i] = (v[i] - mean) * inv;
    if (lane == 0) sqv[row] = qv * inv * inv;
}

// pairwise distances for one (b, 32-i-tile, 16-j-tile); global max via atomic
__global__ __launch_bounds__(256) void dist_kernel(
    const float* __restrict__ feat, const float* __restrict__ sq,
    float* __restrict__ dist, unsigned* __restrict__ dmax)
{
    __shared__ float Fi[32][260];
    __shared__ float Fj[16][260];
    __shared__ float redm[4];
    const int tid = threadIdx.x;
    const int bid = blockIdx.x;
    const int b = bid >> 7, it = (bid >> 4) & 7, jt = bid & 15;
    const float* fb = feat + (size_t)b * 65536;
    for (int idx = tid; idx < 32 * 256; idx += 256) {
        const int r = idx >> 8, e = idx & 255;
        Fi[r][e] = fb[(it * 32 + r) * 256 + e];
    }
    for (int idx = tid; idx < 16 * 256; idx += 256) {
        const int r = idx >> 8, e = idx & 255;
        Fj[r][e] = fb[(jt * 16 + r) * 256 + e];
    }
    __syncthreads();
    const int ii = tid >> 3, j0 = (tid & 7) * 2;
    float acc[2] = {0.f, 0.f};
    for (int e = 0; e < 256; e += 4) {
        const float4 a = *(const float4*)&Fi[ii][e];
#pragma unroll
        for (int u = 0; u < 2; u++) {
            const float4 bv = *(const float4*)&Fj[j0 + u][e];
            acc[u] += a.x * bv.x + a.y * bv.y + a.z * bv.z + a.w * bv.w;
        }
    }
    const float sqi = sq[b * 256 + it * 32 + ii];
    float mymax = 0.f;
#pragma unroll
    for (int u = 0; u < 2; u++) {
        const float d2 = sqi + sq[b * 256 + jt * 16 + j0 + u] - 2.f * acc[u];
        const float d = sqrtf(fmaxf(d2, 0.f));
        dist[((size_t)b * 256 + it * 32 + ii) * 256 + jt * 16 + j0 + u] = d;
        mymax = fmaxf(mymax, d);
    }
    mymax = wave_max(mymax);
    if ((tid & 63) == 0) redm[tid >> 6] = mymax;
    __syncthreads();
    if (tid == 0) {
        const float m = fmaxf(fmaxf(redm[0], redm[1]), fmaxf(redm[2], redm[3]));
        atomicMax(dmax, __float_as_uint(m));
    }
}

// LayerNorm with affine, fp32 in -> bf16 out
__global__ __launch_bounds__(256) void ln_bf_kernel(
    const float* __restrict__ x, const float* __restrict__ g, const float* __restrict__ bta,
    unsigned short* __restrict__ out)
{
    const int tid = threadIdx.x, lane = tid & 63, wid = tid >> 6;
    const int row = blockIdx.x * 4 + wid;
    const float* xr = x + (size_t)row * 256;
    float v[4];
#pragma unroll
    for (int i = 0; i < 4; i++) v[i] = xr[lane + 64 * i];
    float sm = wave_sum(v[0] + v[1] + v[2] + v[3]);
    const float mean = sm * (1.f / 256.f);
    float q = 0.f;
#pragma unroll
    for (int i = 0; i < 4; i++) { const float d = v[i] - mean; q = fmaf(d, d, q); }
    q = wave_sum(q);
    const float inv = rsqrtf(q * (1.f / 256.f) + 1e-5f);
    unsigned short* orow = out + (size_t)row * 256;
#pragma unroll
    for (int i = 0; i < 4; i++) {
        const int e = lane + 64 * i;
        orow[e] = f2bf((v[i] - mean) * inv * g[e] + bta[e]);
    }
}

// Transpose all transformer weights to bf16 Wt[n][k]. grid (16,16,12): z = layer*6 + id
__global__ __launch_bounds__(256) void prep_wt_kernel(
    const float* __restrict__ wq, const float* __restrict__ wk, const float* __restrict__ wv,
    const float* __restrict__ wo, const float* __restrict__ f1, const float* __restrict__ f2,
    unsigned short* __restrict__ wtb)
{
    __shared__ float t[32][33];
    const int z = blockIdx.z;
    const int l = z / 6, id = z % 6;
    const float* src; int K_, N_; size_t doff;
    switch (id) {
        case 0:  src = wq + (size_t)l * 65536;  K_ = 256; N_ = 256; doff = 0;      break;
        case 1:  src = wk + (size_t)l * 65536;  K_ = 256; N_ = 256; doff = 65536;  break;
        case 2:  src = wv + (size_t)l * 65536;  K_ = 256; N_ = 256; doff = 131072; break;
        case 3:  src = wo + (size_t)l * 65536;  K_ = 256; N_ = 256; doff = 196608; break;
        case 4:  src = f1 + (size_t)l * 131072; K_ = 256; N_ = 512; doff = 262144; break;
        default: src = f2 + (size_t)l * 131072; K_ = 512; N_ = 256; doff = 393216; break;
    }
    const int k0 = blockIdx.x * 32, n0 = blockIdx.y * 32;
    if (k0 >= K_ || n0 >= N_) return;
    unsigned short* dst = wtb + (size_t)l * 524288 + doff;
    const int c = threadIdx.x & 31, rq = threadIdx.x >> 5;
#pragma unroll
    for (int i = 0; i < 4; i++) {
        const int r = rq + i * 8;
        t[r][c] = src[(size_t)(k0 + r) * N_ + n0 + c];
    }
    __syncthreads();
#pragma unroll
    for (int i = 0; i < 4; i++) {
        const int r = rq + i * 8;
        dst[(size_t)(n0 + r) * K_ + k0 + c] = f2bf(t[c][r]);
    }
}

// bf16 MFMA GEMM: C[M=2048][N] = A[M][K] @ Wt[N][K]^T (+bias, mode-dependent epilogue)
// grid (8, N/64), block 256 (4 waves, each 64m x 64n).
// mode 0: QKV (N=768): n<256 -> o0=q_bf, <512 -> o1=k_bf, else o2=vt_bf (transposed [b,h,d,j])
// mode 1: fp32 out: outf = acc + b0 + R   (O-proj, FFN2), N=256
// mode 2: relu bf16 out o0, N=512 (FFN1)
__global__ __launch_bounds__(256) void gemm_mfma_kernel(
    const unsigned short* __restrict__ A, const unsigned short* __restrict__ Wt,
    const float* __restrict__ b0, const float* __restrict__ b1, const float* __restrict__ b2,
    const float* __restrict__ R, float* __restrict__ outf,
    unsigned short* __restrict__ o0, unsigned short* __restrict__ o1, unsigned short* __restrict__ o2,
    int K, int mode)
{
    const int tid = threadIdx.x;
    const int lane = tid & 63, lr = lane & 15, quad = lane >> 4;
    const int wv = __builtin_amdgcn_readfirstlane((int)(tid >> 6));
    const int m0 = blockIdx.x * 256 + wv * 64;
    const int n0 = blockIdx.y * 64;

    floatx4 acc[4][4];
#pragma unroll
    for (int r = 0; r < 4; r++)
#pragma unroll
        for (int c = 0; c < 4; c++) acc[r][c] = (floatx4){0.f, 0.f, 0.f, 0.f};

    const unsigned short* Ap = A + (size_t)(m0 + lr) * K + quad * 8;
    const unsigned short* Bp = Wt + (size_t)(n0 + lr) * K + quad * 8;
    const int nks = K >> 5;
#pragma unroll 4
    for (int ks = 0; ks < nks; ks++) {
        const int ko = ks * 32;
        bf16x8 a[4], b[4];
#pragma unroll
        for (int r = 0; r < 4; r++) a[r] = *(const bf16x8*)(Ap + (size_t)r * 16 * K + ko);
#pragma unroll
        for (int c = 0; c < 4; c++) b[c] = *(const bf16x8*)(Bp + (size_t)c * 16 * K + ko);
#pragma unroll
        for (int r = 0; r < 4; r++)
#pragma unroll
            for (int c = 0; c < 4; c++)
                acc[r][c] = __builtin_amdgcn_mfma_f32_16x16x32_bf16(a[r], b[c], acc[r][c], 0, 0, 0);
    }

    if (mode == 0) {
        const int which = n0 >> 8, nn0 = n0 & 255;
        if (which < 2) {
            unsigned short* op = which ? o1 : o0;
            const float* bp = which ? b1 : b0;
#pragma unroll
            for (int r = 0; r < 4; r++)
#pragma unroll
                for (int c = 0; c < 4; c++)
#pragma unroll
                    for (int e = 0; e < 4; e++) {
                        const int m = m0 + r * 16 + quad * 4 + e;
                        const int n = nn0 + c * 16 + lr;
                        op[(size_t)m * 256 + n] = f2bf(acc[r][c][e] + bp[n]);
                    }
        } else {
#pragma unroll
            for (int r = 0; r < 4; r++)
#pragma unroll
                for (int c = 0; c < 4; c++)
#pragma unroll
                    for (int e = 0; e < 4; e++) {
                        const int m = m0 + r * 16 + quad * 4 + e;
                        const int nn = nn0 + c * 16 + lr;
                        const int bb_ = m >> 8, j = m & 255, hh = nn >> 5, d = nn & 31;
                        o2[(size_t)((bb_ * 8 + hh) * 32 + d) * 256 + j] = f2bf(acc[r][c][e] + b2[nn]);
                    }
        }
    } else if (mode == 1) {
#pragma unroll
        for (int r = 0; r < 4; r++)
#pragma unroll
            for (int c = 0; c < 4; c++)
#pragma unroll
                for (int e = 0; e < 4; e++) {
                    const int m = m0 + r * 16 + quad * 4 + e;
                    const int n = n0 + c * 16 + lr;
                    outf[(size_t)m * 256 + n] = acc[r][c][e] + b0[n] + R[(size_t)m * 256 + n];
                }
    } else {
#pragma unroll
        for (int r = 0; r < 4; r++)
#pragma unroll
            for (int c = 0; c < 4; c++)
#pragma unroll
                for (int e = 0; e < 4; e++) {
                    const int m = m0 + r * 16 + quad * 4 + e;
                    const int n = n0 + c * 16 + lr;
                    o0[(size_t)m * 512 + n] = f2bf(fmaxf(acc[r][c][e] + b0[n], 0.f));
                }
    }
}

// MFMA attention: grid (4 ic, 8 h, 8 b), block 256 (4 waves, wave = one 16-i tile)
__global__ __launch_bounds__(256) void attn_mfma_kernel(
    const unsigned short* __restrict__ q_bf, const unsigned short* __restrict__ k_bf,
    const unsigned short* __restrict__ vt_bf,
    const float* __restrict__ dist, const unsigned* __restrict__ dmax,
    const float* __restrict__ bw, const float* __restrict__ bb,
    unsigned short* __restrict__ ao_bf)
{
    __shared__ unsigned short Ps[4][16][264];
    const int tid = threadIdx.x;
    const int lane = tid & 63, lr = lane & 15, quad = lane >> 4;
    const int wv = __builtin_amdgcn_readfirstlane((int)(tid >> 6));
    const int ic = blockIdx.x, hh = blockIdx.y, b = blockIdx.z;
    const int i0 = ic * 64 + wv * 16;

    const float dinv = 1.f / (__uint_as_float(*dmax) + 1e-6f);
    const float w0 = bw[0 * 8 + hh], w1 = bw[1 * 8 + hh], w2 = bw[2 * 8 + hh], w3 = bw[3 * 8 + hh];
    const float bbh = bb[hh];
    const float scale = 0.17677669529663687f;

    // scores: 16 j-tiles, one K=32 MFMA each
    const bf16x8 aq = *(const bf16x8*)(q_bf + (size_t)(b * 256 + i0 + lr) * 256 + hh * 32 + quad * 8);
    floatx4 sc[16];
#pragma unroll
    for (int c = 0; c < 16; c++) {
        const bf16x8 bk = *(const bf16x8*)(k_bf + (size_t)(b * 256 + c * 16 + lr) * 256 + hh * 32 + quad * 8);
        sc[c] = __builtin_amdgcn_mfma_f32_16x16x32_bf16(aq, bk, (floatx4){0.f, 0.f, 0.f, 0.f}, 0, 0, 0);
    }

    // bias + softmax per output row (i = i0 + quad*4 + e), j = c*16 + lr
#pragma unroll
    for (int e = 0; e < 4; e++) {
        const int i = i0 + quad * 4 + e;
        const float* drow = dist + ((size_t)(b * 256 + i)) * 256;
        float bs[16];
        float mx = -1e30f;
#pragma unroll
        for (int c = 0; c < 16; c++) {
            const int j = c * 16 + lr;
            const float dn = drow[j] * dinv;
            const float rd = fabsf((float)(i - j)) * (1.f / 255.f);
            bs[c] = sc[c][e] * scale + w0 * dn + w1 * rd + w2 * (1.f - rd) + w3 * (1.f - dn) + bbh;
            mx = fmaxf(mx, bs[c]);
        }
        mx = fmaxf(mx, __shfl_xor(mx, 1)); mx = fmaxf(mx, __shfl_xor(mx, 2));
        mx = fmaxf(mx, __shfl_xor(mx, 4)); mx = fmaxf(mx, __shfl_xor(mx, 8));
        float sm = 0.f;
#pragma unroll
        for (int c = 0; c < 16; c++) { bs[c] = __expf(bs[c] - mx); sm += bs[c]; }
        sm += __shfl_xor(sm, 1); sm += __shfl_xor(sm, 2);
        sm += __shfl_xor(sm, 4); sm += __shfl_xor(sm, 8);
        const float rs = 1.f / sm;
#pragma unroll
        for (int c = 0; c < 16; c++)
            Ps[wv][quad * 4 + e][c * 16 + lr] = f2bf(bs[c] * rs);
    }
    __syncthreads();

    // O = P @ V : a = P rows (i), b = Vt rows (d), K=256 over j
    floatx4 oc[2];
    oc[0] = (floatx4){0.f, 0.f, 0.f, 0.f};
    oc[1] = (floatx4){0.f, 0.f, 0.f, 0.f};
    const unsigned short* vtb = vt_bf + (size_t)(b * 8 + hh) * 8192;
#pragma unroll
    for (int ks = 0; ks < 8; ks++) {
        const bf16x8 ap = *(const bf16x8*)(&Ps[wv][lr][ks * 32 + quad * 8]);
#pragma unroll
        for (int c2 = 0; c2 < 2; c2++) {
            const bf16x8 bvv = *(const bf16x8*)(vtb + (size_t)(c2 * 16 + lr) * 256 + ks * 32 + quad * 8);
            oc[c2] = __builtin_amdgcn_mfma_f32_16x16x32_bf16(ap, bvv, oc[c2], 0, 0, 0);
        }
    }
#pragma unroll
    for (int c2 = 0; c2 < 2; c2++)
#pragma unroll
        for (int e = 0; e < 4; e++)
            ao_bf[(size_t)(b * 256 + i0 + quad * 4 + e) * 256 + hh * 32 + c2 * 16 + lr] = f2bf(oc[c2][e]);
}

// chunked max-pool over segments + final FC [2048 -> 2]
__global__ __launch_bounds__(256) void pool_fc_kernel(
    const float* __restrict__ h, const float* __restrict__ fcw,
    const float* __restrict__ fcb, float* __restrict__ out)
{
    __shared__ float red[8];
    const int b = blockIdx.x, tid = threadIdx.x, lane = tid & 63, wid = tid >> 6;
    float a0 = 0.f, a1 = 0.f;
    for (int ns = 0; ns < 8; ns++) {
        const float* hp = h + ((size_t)(b * 256 + ns * 32)) * 256 + tid;
        float m = hp[0];
#pragma unroll
        for (int r = 1; r < 32; r++) m = fmaxf(m, hp[(size_t)r * 256]);
        a0 = fmaf(m, fcw[(ns * 256 + tid) * 2 + 0], a0);
        a1 = fmaf(m, fcw[(ns * 256 + tid) * 2 + 1], a1);
    }
    a0 = wave_sum(a0);
    a1 = wave_sum(a1);
    if (lane == 0) { red[wid] = a0; red[4 + wid] = a1; }
    __syncthreads();
    if (tid == 0) out[b * 2 + 0] = red[0] + red[1] + red[2] + red[3] + fcb[0];
    if (tid == 1) out[b * 2 + 1] = red[4] + red[5] + red[6] + red[7] + fcb[1];
}

extern "C" void kernel_launch(void* const* d_in, const int* in_sizes, int n_in,
                              void* d_out, int out_size, void* d_ws, size_t ws_size,
                              hipStream_t stream)
{
    (void)in_sizes; (void)n_in; (void)out_size; (void)ws_size;
    const float* x       = (const float*)d_in[0];
    const float* conv1_w = (const float*)d_in[1];
    const float* conv1_b = (const float*)d_in[2];
    const float* conv2_w = (const float*)d_in[3];
    const float* conv2_b = (const float*)d_in[4];
    const float* ln1_g   = (const float*)d_in[5];
    const float* ln1_b   = (const float*)d_in[6];
    const float* wq = (const float*)d_in[7];  const float* bq = (const float*)d_in[8];
    const float* wk = (const float*)d_in[9];  const float* bk = (const float*)d_in[10];
    const float* wvp = (const float*)d_in[11]; const float* bv = (const float*)d_in[12];
    const float* wo = (const float*)d_in[13]; const float* bo = (const float*)d_in[14];
    const float* bias_w = (const float*)d_in[15];
    const float* bias_b = (const float*)d_in[16];
    const float* ln2_g  = (const float*)d_in[17];
    const float* ln2_b  = (const float*)d_in[18];
    const float* ffn_w1 = (const float*)d_in[19]; const float* ffn_b1 = (const float*)d_in[20];
    const float* ffn_w2 = (const float*)d_in[21]; const float* ffn_b2 = (const float*)d_in[22];
    const float* fc_w   = (const float*)d_in[23]; const float* fc_b = (const float*)d_in[24];
    float* out = (float*)d_out;

    float* ws = (float*)d_ws;
    float* h    = ws;                         // [2048,256] fp32
    float* dist = h + 524288;                 // [8,256,256] fp32
    float* sqv  = dist + 524288;              // [2048]
    unsigned* dmax = (unsigned*)(sqv + 2048);
    unsigned* cnnmax = (unsigned*)(sqv + 2048 + 16);              // [2048,256]
    unsigned short* hn_bf = (unsigned short*)(sqv + 2048 + 16 + 524288);  // [2048,256]
    unsigned short* q_bf  = hn_bf + 524288;
    unsigned short* k_bf  = q_bf + 524288;
    unsigned short* vt_bf = k_bf + 524288;    // [8,8,32,256] = [b,h,d,j]
    unsigned short* ao_bf = vt_bf + 524288;   // [2048,256]
    unsigned short* fm_bf = ao_bf + 524288;   // [2048,512]
    unsigned short* wtb   = fm_bf + 1048576;  // [2][524288]
    unsigned short* w2b   = wtb + 1048576;    // 64*256*384
    unsigned short* h1b   = w2b + 6291456;    // 64*2048*128

    init_kernel<<<2048, 256, 0, stream>>>(dmax, cnnmax);
    prep_wt_kernel<<<dim3(16, 16, 12), 256, 0, stream>>>(wq, wk, wvp, wo, ffn_w1, ffn_w2, wtb);
    for (int g = 0; g < 4; g++) {
        const int s0 = g * 64;
        prep_w2_kernel<<<dim3(256, 64), 256, 0, stream>>>(conv2_w, w2b, s0);
        conv1_kernel<<<dim3(64, 8), 256, 0, stream>>>(x, conv1_w, conv1_b, h1b, s0);
        conv2_mfma_kernel<<<dim3(16, 64), 512, 0, stream>>>(w2b, h1b, conv2_b, cnnmax, s0);
    }
    ln0_kernel<<<512, 256, 0, stream>>>(cnnmax, h, sqv);
    dist_kernel<<<1024, 256, 0, stream>>>(h, sqv, dist, dmax);

    for (int l = 0; l < 2; l++) {
        const unsigned short* wqkvT = wtb + (size_t)l * 524288;
        const unsigned short* woT   = wqkvT + 196608;
        const unsigned short* f1T   = wqkvT + 262144;
        const unsigned short* f2T   = wqkvT + 393216;

        ln_bf_kernel<<<512, 256, 0, stream>>>(h, ln1_g + l * 256, ln1_b + l * 256, hn_bf);
        gemm_mfma_kernel<<<dim3(8, 12), 256, 0, stream>>>(
            hn_bf, wqkvT, bq + l * 256, bk + l * 256, bv + l * 256,
            nullptr, nullptr, q_bf, k_bf, vt_bf, 256, 0);
        attn_mfma_kernel<<<dim3(4, 8, 8), 256, 0, stream>>>(
            q_bf, k_bf, vt_bf, dist, dmax, bias_w + l * 32, bias_b + l * 8, ao_bf);
        gemm_mfma_kernel<<<dim3(8, 4), 256, 0, stream>>>(
            ao_bf, woT, bo + l * 256, nullptr, nullptr,
            h, h, nullptr, nullptr, nullptr, 256, 1);
        ln_bf_kernel<<<512, 256, 0, stream>>>(h, ln2_g + l * 256, ln2_b + l * 256, hn_bf);
        gemm_mfma_kernel<<<dim3(8, 8), 256, 0, stream>>>(
            hn_bf, f1T, ffn_b1 + l * 512, nullptr, nullptr,
            nullptr, nullptr, fm_bf, nullptr, nullptr, 256, 2);
        gemm_mfma_kernel<<<dim3(8, 4), 256, 0, stream>>>(
            fm_bf, f2T, ffn_b2 + l * 256, nullptr, nullptr,
            h, h, nullptr, nullptr, nullptr, 512, 1);
    }
    pool_fc_kernel<<<8, 256, 0, stream>>>(h, fc_w, fc_b, out);
}